// Round 1
// 556.036 us; speedup vs baseline: 1.0163x; 1.0163x over previous
//
#include <hip/hip_runtime.h>
#include <math.h>

// Problem constants
#define BB   128
#define NN   196
#define CC   768
#define HH   4
#define DD   192
#define TOK_PER   19267584   // 128*196*768
#define NROWS_ALL 75264      // 3*128*196
#define F4_ALL    14450688   // NROWS_ALL * 192
#define NUM_KEEP  118
#define SCALE_D   0.07216878364870322f   // 192^-0.5

// workspace layout (in floats)
#define OFF_QPART 0
#define SZ_QPART  (2*9*128*768)
#define OFF_VV    (OFF_QPART + SZ_QPART)
#define SZ_VV     (9*128*4*768)
#define OFF_BIAS  (OFF_VV + SZ_VV)
#define SZ_BIAS   (9*128*4)
#define OFF_GN    (OFF_BIAS + SZ_BIAS)   // unused now (gnorm fused into k_dots2)
#define SZ_GN     (3*128*768)
#define OFF_SC    (OFF_GN + SZ_GN)
#define SZ_SC     (3*128*196*16)

__device__ __forceinline__ float4 f4fma(float s, float4 b, float4 a) {
  a.x = fmaf(s, b.x, a.x); a.y = fmaf(s, b.y, a.y);
  a.z = fmaf(s, b.z, a.z); a.w = fmaf(s, b.w, a.w);
  return a;
}
__device__ __forceinline__ float f4dot(float4 p, float4 q) {
  return p.x*q.x + p.y*q.y + p.z*q.z + p.w*q.w;
}

// ---------------------------------------------------------------------------
// q partial GEMM: qpart[z][i][b][o] = sum_{c in half z} g_{gi}[b][c] * qw[i][o][c]
__global__ __launch_bounds__(256) void k_qproj(const float* __restrict__ g0,
                                               const float* __restrict__ g1,
                                               const float* __restrict__ g2,
                                               const float* __restrict__ qw,
                                               float* __restrict__ qpart) {
  __shared__ __align__(16) float AsT[32 * 68];
  __shared__ __align__(16) float WsT[32 * 68];
  const int gtab[9] = {0, 1, 2, 1, 0, 2, 2, 0, 1};
  int i = blockIdx.y, z = blockIdx.z;
  int mt = blockIdx.x & 1, nt = blockIdx.x >> 1;
  int tid = threadIdx.x, tx = tid & 15, ty = tid >> 4;
  int gi = gtab[i];
  const float4* A4 = (const float4*)((gi == 0) ? g0 : ((gi == 1) ? g1 : g2));
  const float4* W4 = (const float4*)(qw + (size_t)i * CC * CC);
  float4 acc0 = {0,0,0,0}, acc1 = {0,0,0,0}, acc2 = {0,0,0,0}, acc3 = {0,0,0,0};
  int arow = mt * 64, wrow = nt * 64;
  int kb4 = z * 96;  // float4 units
  for (int kk = 0; kk < 12; kk++) {
    #pragma unroll
    for (int f = tid; f < 512; f += 256) {
      int r = f >> 3, k4 = f & 7;
      float4 va = A4[(size_t)(arow + r) * 192 + kb4 + kk * 8 + k4];
      float4 vw = W4[(size_t)(wrow + r) * 192 + kb4 + kk * 8 + k4];
      int kq = 4 * k4;
      AsT[(kq+0)*68 + r] = va.x; AsT[(kq+1)*68 + r] = va.y;
      AsT[(kq+2)*68 + r] = va.z; AsT[(kq+3)*68 + r] = va.w;
      WsT[(kq+0)*68 + r] = vw.x; WsT[(kq+1)*68 + r] = vw.y;
      WsT[(kq+2)*68 + r] = vw.z; WsT[(kq+3)*68 + r] = vw.w;
    }
    __syncthreads();
    #pragma unroll
    for (int k = 0; k < 32; k++) {
      float4 a = *(const float4*)&AsT[k * 68 + 4 * ty];
      float4 w = *(const float4*)&WsT[k * 68 + 4 * tx];
      acc0 = f4fma(a.x, w, acc0); acc1 = f4fma(a.y, w, acc1);
      acc2 = f4fma(a.z, w, acc2); acc3 = f4fma(a.w, w, acc3);
    }
    __syncthreads();
  }
  float* dst = qpart + (size_t)(z * 9 + i) * 128 * CC;
  int col = wrow + 4 * tx;
  int row = arow + 4 * ty;
  *(float4*)&dst[(size_t)(row + 0) * CC + col] = acc0;
  *(float4*)&dst[(size_t)(row + 1) * CC + col] = acc1;
  *(float4*)&dst[(size_t)(row + 2) * CC + col] = acc2;
  *(float4*)&dst[(size_t)(row + 3) * CC + col] = acc3;
}

// ---------------------------------------------------------------------------
// vv GEMM: vv[i][b][h][c] = sum_j (qpart0+qpart1+qb)[i][b][h*192+j] * kw[i][h*192+j][c]
__global__ __launch_bounds__(256) void k_vvproj(const float* __restrict__ qpart,
                                                const float* __restrict__ qb,
                                                const float* __restrict__ kw,
                                                float* __restrict__ vvout) {
  __shared__ __align__(16) float AsT[32 * 68];
  __shared__ __align__(16) float Bs[32 * 68];
  int ih = blockIdx.y; int i = ih >> 2, h = ih & 3;
  int mt = blockIdx.x & 1, nt = blockIdx.x >> 1;
  int tid = threadIdx.x, tx = tid & 15, ty = tid >> 4;
  const float4* qp0 = (const float4*)qpart + (size_t)i * 128 * 192;
  const float4* qp1 = (const float4*)qpart + (size_t)(9 + i) * 128 * 192;
  const float4* qb4 = (const float4*)qb + (size_t)i * 192;
  const float4* B4  = (const float4*)(kw + (size_t)i * CC * CC);
  float4 acc0 = {0,0,0,0}, acc1 = {0,0,0,0}, acc2 = {0,0,0,0}, acc3 = {0,0,0,0};
  int arow = mt * 64;
  int bcol4 = nt * 16;
  for (int kk = 0; kk < 6; kk++) {
    #pragma unroll
    for (int f = tid; f < 512; f += 256) {
      int r = f >> 3, k4 = f & 7;
      int colf4 = h * 48 + kk * 8 + k4;
      float4 va = qp0[(size_t)(arow + r) * 192 + colf4];
      float4 vb = qp1[(size_t)(arow + r) * 192 + colf4];
      float4 vq = qb4[colf4];
      va.x += vb.x + vq.x; va.y += vb.y + vq.y;
      va.z += vb.z + vq.z; va.w += vb.w + vq.w;
      int kq = 4 * k4;
      AsT[(kq+0)*68 + r] = va.x; AsT[(kq+1)*68 + r] = va.y;
      AsT[(kq+2)*68 + r] = va.z; AsT[(kq+3)*68 + r] = va.w;
      int rk = f >> 4, c4 = f & 15;
      float4 vB = B4[(size_t)(h * DD + kk * 32 + rk) * 192 + bcol4 + c4];
      *(float4*)&Bs[rk * 68 + 4 * c4] = vB;
    }
    __syncthreads();
    #pragma unroll
    for (int k = 0; k < 32; k++) {
      float4 a = *(const float4*)&AsT[k * 68 + 4 * ty];
      float4 bb = *(const float4*)&Bs[k * 68 + 4 * tx];
      acc0 = f4fma(a.x, bb, acc0); acc1 = f4fma(a.y, bb, acc1);
      acc2 = f4fma(a.z, bb, acc2); acc3 = f4fma(a.w, bb, acc3);
    }
    __syncthreads();
  }
  int col = nt * 64 + 4 * tx;
  int b0 = arow + 4 * ty;
  *(float4*)&vvout[((size_t)(i * 128 + b0 + 0) * 4 + h) * CC + col] = acc0;
  *(float4*)&vvout[((size_t)(i * 128 + b0 + 1) * 4 + h) * CC + col] = acc1;
  *(float4*)&vvout[((size_t)(i * 128 + b0 + 2) * 4 + h) * CC + col] = acc2;
  *(float4*)&vvout[((size_t)(i * 128 + b0 + 3) * 4 + h) * CC + col] = acc3;
}

// ---------------------------------------------------------------------------
// bias[i][b][h] = sum_j (q0+q1+qb)[i][b][h*192+j] * kb[i][h*192+j]
// Coalesced rewrite: lanes span j (contiguous 256 B loads), butterfly reduce.
__global__ __launch_bounds__(256) void k_bias(const float* __restrict__ qpart,
                                              const float* __restrict__ qb,
                                              const float* __restrict__ kb,
                                              float* __restrict__ bias) {
  int ih = blockIdx.x; int i = ih >> 2, h = ih & 3;
  int w = threadIdx.x >> 6, lane = threadIdx.x & 63;
  const float* qbb = qb + (size_t)i * CC + h * DD;
  const float* kbb = kb + (size_t)i * CC + h * DD;
  float kb0 = kbb[lane], kb1 = kbb[lane + 64], kb2 = kbb[lane + 128];
  float qb0 = qbb[lane], qb1 = qbb[lane + 64], qb2 = qbb[lane + 128];
  const float* q0base = qpart + (size_t)i * 128 * CC + h * DD;
  const float* q1base = qpart + (size_t)(9 + i) * 128 * CC + h * DD;
  for (int b = w; b < 128; b += 4) {
    const float* q0 = q0base + (size_t)b * CC;
    const float* q1 = q1base + (size_t)b * CC;
    float s = (q0[lane]       + q1[lane]       + qb0) * kb0
            + (q0[lane + 64]  + q1[lane + 64]  + qb1) * kb1
            + (q0[lane + 128] + q1[lane + 128] + qb2) * kb2;
    #pragma unroll
    for (int off = 32; off; off >>= 1) s += __shfl_xor(s, off);
    if (lane == 0) bias[((size_t)i * 128 + b) * 4 + h] = s;
  }
}

// ---------------------------------------------------------------------------
// k_dots v3: fused gnorm (LDS), vmcnt no longer drained per row, prefetch
// issued before the FMA phase so HBM latency hides under compute.
// Writes sc[t][b][n][16]: 0..11 = scaled+biased logits (k*4+h),
// 12..14 = cos for module k, 15 = unused.
__global__ __launch_bounds__(256, 2) void k_dots2(const float* __restrict__ rgb,
                                                  const float* __restrict__ ni,
                                                  const float* __restrict__ ti,
                                                  const float* __restrict__ vv,
                                                  const float* __restrict__ g0,
                                                  const float* __restrict__ g1,
                                                  const float* __restrict__ g2,
                                                  const float* __restrict__ bias,
                                                  float* __restrict__ sc) {
  __shared__ float red[4][64 * 17];
  __shared__ __align__(16) float GN[3 * CC];   // 3 normalized global vectors
  int bid = blockIdx.x;
  int t = bid >> 8;
  int rem = bid & 255;
  int b = rem >> 1, half = rem & 1;
  int tid = threadIdx.x;
  int w = tid >> 6, lane = tid & 63;
  const float* toks = (t == 0) ? rgb : ((t == 1) ? ni : ti);
  int gi0, gi1, gi2;
  if (t == 0)      { gi0 = 0; gi1 = 1; gi2 = 2; }
  else if (t == 1) { gi0 = 1; gi1 = 0; gi2 = 2; }
  else             { gi0 = 2; gi1 = 0; gi2 = 1; }

  // fused gnorm: waves 0..2 each normalize one global vector into LDS
  if (w < 3) {
    int gidx = (w == 0) ? gi0 : ((w == 1) ? gi1 : gi2);
    const float* gsrc = (gidx == 0) ? g0 : ((gidx == 1) ? g1 : g2);
    const float4* s4 = (const float4*)(gsrc + (size_t)b * CC);
    float4 u0 = s4[lane], u1 = s4[lane + 64], u2 = s4[lane + 128];
    float ss = f4dot(u0, u0) + f4dot(u1, u1) + f4dot(u2, u2);
    #pragma unroll
    for (int off = 32; off; off >>= 1) ss += __shfl_xor(ss, off);
    float inv = 1.0f / fmaxf(sqrtf(ss), 1e-12f);
    u0.x *= inv; u0.y *= inv; u0.z *= inv; u0.w *= inv;
    u1.x *= inv; u1.y *= inv; u1.z *= inv; u1.w *= inv;
    u2.x *= inv; u2.y *= inv; u2.z *= inv; u2.w *= inv;
    float4* d4 = (float4*)&GN[w * CC];
    d4[lane] = u0; d4[lane + 64] = u1; d4[lane + 128] = u2;
  }

  // 12 vv vectors in registers (144 VGPRs; gn moved to LDS for headroom)
  float4 V[36];
  #pragma unroll
  for (int k = 0; k < 3; k++) {
    #pragma unroll
    for (int h = 0; h < 4; h++) {
      const float4* src = (const float4*)(vv + (((size_t)(3*t + k) * 128 + b) * 4 + h) * CC);
      int v = k * 4 + h;
      V[3*v + 0] = src[lane];
      V[3*v + 1] = src[lane + 64];
      V[3*v + 2] = src[lane + 128];
    }
  }

  int a_id = lane & 15;
  float bias_r = 0.f;
  if (a_id < 12)
    bias_r = bias[((size_t)(3*t + (a_id >> 2)) * 128 + b) * 4 + (a_id & 3)];

  __syncthreads();   // GN visible to all waves

  float* myred = red[w];
  const float4* G4 = (const float4*)GN;
  int s_grp = lane >> 4;
  int n0 = half * 98;

  // first row load (row_local = w, always < 98)
  const float4* pr0 = (const float4*)(toks + ((size_t)b * NN + n0 + w) * CC);
  float4 pc0 = pr0[lane], pc1 = pr0[lane + 64], pc2 = pr0[lane + 128];

  for (int it = 0; it < 25; it++) {
    int row_local = it * 4 + w;
    if (row_local >= 98) break;          // wave-uniform

    // ---- issue next-row prefetch FIRST: covered by FMA + reduce phases
    int rl_next = row_local + 4;
    float4 pn0 = pc0, pn1 = pc1, pn2 = pc2;
    if (rl_next < 98) {
      const float4* pr = (const float4*)(toks + ((size_t)b * NN + n0 + rl_next) * CC);
      pn0 = pr[lane]; pn1 = pr[lane + 64]; pn2 = pr[lane + 128];
    }

    // ---- FMA phase: 16 partial dots over this lane's 12 columns
    float a[16];
    #pragma unroll
    for (int v = 0; v < 12; v++)
      a[v] = f4dot(pc0, V[3*v]) + f4dot(pc1, V[3*v + 1]) + f4dot(pc2, V[3*v + 2]);
    #pragma unroll
    for (int j = 0; j < 3; j++)
      a[12 + j] = f4dot(pc0, G4[j*192 + lane])
                + f4dot(pc1, G4[j*192 + lane + 64])
                + f4dot(pc2, G4[j*192 + lane + 128]);
    a[15] = f4dot(pc0, pc0) + f4dot(pc1, pc1) + f4dot(pc2, pc2);

    // ---- reduce via LDS transpose (wave-private, no barrier)
    #pragma unroll
    for (int v = 0; v < 16; v++) myred[lane * 17 + v] = a[v];
    __builtin_amdgcn_s_waitcnt(0xc07f);  // lgkmcnt(0) ONLY — keep prefetch in flight
    __builtin_amdgcn_sched_barrier(0);
    float part = 0.f;
    #pragma unroll
    for (int i2 = 0; i2 < 16; i2++)
      part += myred[(s_grp * 16 + i2) * 17 + a_id];
    part += __shfl_xor(part, 16, 64);
    part += __shfl_xor(part, 32, 64);
    // all lanes now hold the full sum for slot a_id

    float s15  = __shfl(part, 15, 64);   // self dot-product
    float invp = 1.0f / fmaxf(sqrtf(s15), 1e-12f);
    float res;
    if (a_id < 12)      res = (part + bias_r) * SCALE_D;
    else if (a_id < 15) res = part * invp;
    else                res = invp;

    if (lane < 16) {
      float* scrow = sc + (((size_t)t * 128 + b) * 196 + (n0 + row_local)) * 16;
      scrow[lane] = res;
    }
    pc0 = pn0; pc1 = pn1; pc2 = pn2;
  }
}

// ---------------------------------------------------------------------------
// k_score v2: column-parallel wave reductions over an LDS tile.
// ~5 barriers/block instead of ~54. Column max is order-invariant, so exp
// values match the old kernel bitwise; only sum orders differ (ulp noise,
// far below the ranking margins).
__global__ __launch_bounds__(256) void k_score(const float* __restrict__ sc,
                                               const float* __restrict__ modal_w,
                                               float* __restrict__ outmask) {
  __shared__ float S[196 * 17];        // row-major, stride 17 (2-way banks = free)
  __shared__ float CSUM[12];
  __shared__ float SV[3][196];
  __shared__ float MN[3], MX[3];
  __shared__ float sfinal[196];
  int b = blockIdx.x, m = blockIdx.y;
  int tid = threadIdx.x;
  int w = tid >> 6, lane = tid & 63;
  bool act = tid < NN;

  // phase 1: stage rows (coalesced 64 B/thread)
  const float4* base = (const float4*)(sc + ((size_t)m * 128 + b) * 196 * 16);
  if (act) {
    float4 r0 = base[tid*4+0], r1 = base[tid*4+1], r2 = base[tid*4+2], r3 = base[tid*4+3];
    float* d = &S[tid * 17];
    d[0] = r0.x; d[1] = r0.y; d[2]  = r0.z; d[3]  = r0.w;
    d[4] = r1.x; d[5] = r1.y; d[6]  = r1.z; d[7]  = r1.w;
    d[8] = r2.x; d[9] = r2.y; d[10] = r2.z; d[11] = r2.w;
    d[12] = r3.x; d[13] = r3.y; d[14] = r3.z;
  }
  __syncthreads();

  // phase 2: per-(k,h) column max + exp-sum; wave w owns columns w, w+4, w+8.
  // exp(v-max) written back in place (computed once).
  #pragma unroll
  for (int c = w; c < 12; c += 4) {
    int n3 = lane + 192;
    float v0 = S[(lane      ) * 17 + c];
    float v1 = S[(lane +  64) * 17 + c];
    float v2 = S[(lane + 128) * 17 + c];
    float v3 = (n3 < NN) ? S[n3 * 17 + c] : -3.4e38f;
    float mx = fmaxf(fmaxf(v0, v1), fmaxf(v2, v3));
    #pragma unroll
    for (int off = 32; off; off >>= 1) mx = fmaxf(mx, __shfl_xor(mx, off));
    float e0 = expf(v0 - mx), e1 = expf(v1 - mx), e2 = expf(v2 - mx);
    float e3 = (n3 < NN) ? expf(v3 - mx) : 0.f;
    float es = e0 + e1 + e2 + e3;
    #pragma unroll
    for (int off = 32; off; off >>= 1) es += __shfl_xor(es, off);
    S[(lane      ) * 17 + c] = e0;
    S[(lane +  64) * 17 + c] = e1;
    S[(lane + 128) * 17 + c] = e2;
    if (n3 < NN) S[n3 * 17 + c] = e3;
    if (lane == 0) CSUM[c] = es;
  }
  __syncthreads();

  // phase 3: per-row combine (e/s matches old division form)
  float scv0 = 0.f, scv1 = 0.f, scv2 = 0.f;
  if (act) {
    const float* r = &S[tid * 17];
    float as0 = r[0]/CSUM[0] + r[1]/CSUM[1] + r[2]/CSUM[2]  + r[3]/CSUM[3];
    float as1 = r[4]/CSUM[4] + r[5]/CSUM[5] + r[6]/CSUM[6]  + r[7]/CSUM[7];
    float as2 = r[8]/CSUM[8] + r[9]/CSUM[9] + r[10]/CSUM[10] + r[11]/CSUM[11];
    scv0 = r[12] * as0 * 0.25f;
    scv1 = r[13] * as1 * 0.25f;
    scv2 = r[14] * as2 * 0.25f;
    SV[0][tid] = scv0; SV[1][tid] = scv1; SV[2][tid] = scv2;
  }
  __syncthreads();

  // phase 4: min/max per k (waves 0..2)
  if (w < 3) {
    float u0 = SV[w][lane], u1 = SV[w][lane + 64], u2 = SV[w][lane + 128];
    float mn = fminf(fminf(u0, u1), u2);
    float mx = fmaxf(fmaxf(u0, u1), u2);
    if (lane + 192 < NN) {
      float u3 = SV[w][lane + 192];
      mn = fminf(mn, u3); mx = fmaxf(mx, u3);
    }
    #pragma unroll
    for (int off = 32; off; off >>= 1) {
      mn = fminf(mn, __shfl_xor(mn, off));
      mx = fmaxf(mx, __shfl_xor(mx, off));
    }
    if (lane == 0) { MN[w] = mn; MX[w] = mx; }
  }
  __syncthreads();

  // phase 5: modal softmax mix + final score
  float w0 = modal_w[m * 3 + 0], w1 = modal_w[m * 3 + 1], w2 = modal_w[m * 3 + 2];
  float wm = fmaxf(w0, fmaxf(w1, w2));
  float ew0 = expf(w0 - wm), ew1 = expf(w1 - wm), ew2 = expf(w2 - wm);
  float esum = ew0 + ew1 + ew2;
  float fv = 0.f;
  if (act) {
    fv = (ew0 / esum) * (scv0 - MN[0]) / (MX[0] - MN[0] + 1e-8f)
       + (ew1 / esum) * (scv1 - MN[1]) / (MX[1] - MN[1] + 1e-8f)
       + (ew2 / esum) * (scv2 - MN[2]) / (MX[2] - MN[2] + 1e-8f);
    sfinal[tid] = fv;
  }
  __syncthreads();

  // phase 6: rank by count (stable descending, ties -> lower index wins)
  if (act) {
    int cnt = 0;
    for (int j = 0; j < NN; j++) {
      float fj = sfinal[j];
      cnt += (fj > fv) || (fj == fv && j < tid);
    }
    outmask[((size_t)m * 128 + b) * NN + tid] = (cnt < NUM_KEEP) ? 1.0f : 0.0f;
  }
}

// ---------------------------------------------------------------------------
// Masked token write: out[r][c] = mask[r] ? tok[r][c] : 0
__global__ __launch_bounds__(256) void k_write(const float* __restrict__ rgb,
                                               const float* __restrict__ ni,
                                               const float* __restrict__ ti,
                                               const float* __restrict__ maskbuf,
                                               float* __restrict__ out) {
  int idx = blockIdx.x * 256 + threadIdx.x;   // < F4_ALL
  int r = idx / 192;
  int c4 = idx - r * 192;
  int m = r / 25088;
  int rb = r - m * 25088;
  float mv = maskbuf[r];
  const float* src = (m == 0) ? rgb : ((m == 1) ? ni : ti);
  float4 o = {0.f, 0.f, 0.f, 0.f};
  if (mv != 0.0f) o = ((const float4*)src)[(size_t)rb * 192 + c4];
  ((float4*)out)[idx] = o;
}

// ---------------------------------------------------------------------------
extern "C" void kernel_launch(void* const* d_in, const int* in_sizes, int n_in,
                              void* d_out, int out_size, void* d_ws, size_t ws_size,
                              hipStream_t stream) {
  const float* rgb = (const float*)d_in[0];
  const float* ni  = (const float*)d_in[1];
  const float* ti  = (const float*)d_in[2];
  const float* g0  = (const float*)d_in[3];
  const float* g1  = (const float*)d_in[4];
  const float* g2  = (const float*)d_in[5];
  const float* qw  = (const float*)d_in[6];
  const float* qb  = (const float*)d_in[7];
  const float* kw  = (const float*)d_in[8];
  const float* kb  = (const float*)d_in[9];
  const float* mw  = (const float*)d_in[10];

  float* ws    = (float*)d_ws;
  float* qpart = ws + OFF_QPART;
  float* vv    = ws + OFF_VV;
  float* bias  = ws + OFF_BIAS;
  float* sc    = ws + OFF_SC;
  float* outf  = (float*)d_out;
  float* maskb = outf + (size_t)3 * TOK_PER;

  k_qproj<<<dim3(24, 9, 2), 256, 0, stream>>>(g0, g1, g2, qw, qpart);
  k_vvproj<<<dim3(24, 36), 256, 0, stream>>>(qpart, qb, kw, vv);
  k_bias<<<36, 256, 0, stream>>>(qpart, qb, kb, bias);
  k_dots2<<<768, 256, 0, stream>>>(rgb, ni, ti, vv, g0, g1, g2, bias, sc);
  k_score<<<dim3(128, 3), 256, 0, stream>>>(sc, mw, maskb);
  k_write<<<F4_ALL / 256, 256, 0, stream>>>(rgb, ni, ti, maskb, outf);
}

// Round 2
// 525.868 us; speedup vs baseline: 1.0746x; 1.0574x over previous
//
#include <hip/hip_runtime.h>
#include <math.h>

// Problem constants
#define BB   128
#define NN   196
#define CC   768
#define HH   4
#define DD   192
#define TOK_PER   19267584   // 128*196*768
#define NROWS_ALL 75264      // 3*128*196
#define NUM_KEEP  118
#define SCALE_D   0.07216878364870322f   // 192^-0.5

// workspace layout (in floats)
#define OFF_QPART 0
#define SZ_QPART  (2*9*128*768)
#define OFF_VV    (OFF_QPART + SZ_QPART)
#define SZ_VV     (9*128*4*768)

__device__ __forceinline__ float4 f4fma(float s, float4 b, float4 a) {
  a.x = fmaf(s, b.x, a.x); a.y = fmaf(s, b.y, a.y);
  a.z = fmaf(s, b.z, a.z); a.w = fmaf(s, b.w, a.w);
  return a;
}
__device__ __forceinline__ float f4dot(float4 p, float4 q) {
  return p.x*q.x + p.y*q.y + p.z*q.z + p.w*q.w;
}

// ---------------------------------------------------------------------------
// q partial GEMM: qpart[z][i][b][o] = sum_{c in half z} g_{gi}[b][c] * qw[i][o][c]
__global__ __launch_bounds__(256) void k_qproj(const float* __restrict__ g0,
                                               const float* __restrict__ g1,
                                               const float* __restrict__ g2,
                                               const float* __restrict__ qw,
                                               float* __restrict__ qpart) {
  __shared__ __align__(16) float AsT[32 * 68];
  __shared__ __align__(16) float WsT[32 * 68];
  const int gtab[9] = {0, 1, 2, 1, 0, 2, 2, 0, 1};
  int i = blockIdx.y, z = blockIdx.z;
  int mt = blockIdx.x & 1, nt = blockIdx.x >> 1;
  int tid = threadIdx.x, tx = tid & 15, ty = tid >> 4;
  int gi = gtab[i];
  const float4* A4 = (const float4*)((gi == 0) ? g0 : ((gi == 1) ? g1 : g2));
  const float4* W4 = (const float4*)(qw + (size_t)i * CC * CC);
  float4 acc0 = {0,0,0,0}, acc1 = {0,0,0,0}, acc2 = {0,0,0,0}, acc3 = {0,0,0,0};
  int arow = mt * 64, wrow = nt * 64;
  int kb4 = z * 96;  // float4 units
  for (int kk = 0; kk < 12; kk++) {
    #pragma unroll
    for (int f = tid; f < 512; f += 256) {
      int r = f >> 3, k4 = f & 7;
      float4 va = A4[(size_t)(arow + r) * 192 + kb4 + kk * 8 + k4];
      float4 vw = W4[(size_t)(wrow + r) * 192 + kb4 + kk * 8 + k4];
      int kq = 4 * k4;
      AsT[(kq+0)*68 + r] = va.x; AsT[(kq+1)*68 + r] = va.y;
      AsT[(kq+2)*68 + r] = va.z; AsT[(kq+3)*68 + r] = va.w;
      WsT[(kq+0)*68 + r] = vw.x; WsT[(kq+1)*68 + r] = vw.y;
      WsT[(kq+2)*68 + r] = vw.z; WsT[(kq+3)*68 + r] = vw.w;
    }
    __syncthreads();
    #pragma unroll
    for (int k = 0; k < 32; k++) {
      float4 a = *(const float4*)&AsT[k * 68 + 4 * ty];
      float4 w = *(const float4*)&WsT[k * 68 + 4 * tx];
      acc0 = f4fma(a.x, w, acc0); acc1 = f4fma(a.y, w, acc1);
      acc2 = f4fma(a.z, w, acc2); acc3 = f4fma(a.w, w, acc3);
    }
    __syncthreads();
  }
  float* dst = qpart + (size_t)(z * 9 + i) * 128 * CC;
  int col = wrow + 4 * tx;
  int row = arow + 4 * ty;
  *(float4*)&dst[(size_t)(row + 0) * CC + col] = acc0;
  *(float4*)&dst[(size_t)(row + 1) * CC + col] = acc1;
  *(float4*)&dst[(size_t)(row + 2) * CC + col] = acc2;
  *(float4*)&dst[(size_t)(row + 3) * CC + col] = acc3;
}

// ---------------------------------------------------------------------------
// vv GEMM: vv[i][b][h][c] = sum_j (qpart0+qpart1+qb)[i][b][h*192+j] * kw[i][h*192+j][c]
__global__ __launch_bounds__(256) void k_vvproj(const float* __restrict__ qpart,
                                                const float* __restrict__ qb,
                                                const float* __restrict__ kw,
                                                float* __restrict__ vvout) {
  __shared__ __align__(16) float AsT[32 * 68];
  __shared__ __align__(16) float Bs[32 * 68];
  int ih = blockIdx.y; int i = ih >> 2, h = ih & 3;
  int mt = blockIdx.x & 1, nt = blockIdx.x >> 1;
  int tid = threadIdx.x, tx = tid & 15, ty = tid >> 4;
  const float4* qp0 = (const float4*)qpart + (size_t)i * 128 * 192;
  const float4* qp1 = (const float4*)qpart + (size_t)(9 + i) * 128 * 192;
  const float4* qb4 = (const float4*)qb + (size_t)i * 192;
  const float4* B4  = (const float4*)(kw + (size_t)i * CC * CC);
  float4 acc0 = {0,0,0,0}, acc1 = {0,0,0,0}, acc2 = {0,0,0,0}, acc3 = {0,0,0,0};
  int arow = mt * 64;
  int bcol4 = nt * 16;
  for (int kk = 0; kk < 6; kk++) {
    #pragma unroll
    for (int f = tid; f < 512; f += 256) {
      int r = f >> 3, k4 = f & 7;
      int colf4 = h * 48 + kk * 8 + k4;
      float4 va = qp0[(size_t)(arow + r) * 192 + colf4];
      float4 vb = qp1[(size_t)(arow + r) * 192 + colf4];
      float4 vq = qb4[colf4];
      va.x += vb.x + vq.x; va.y += vb.y + vq.y;
      va.z += vb.z + vq.z; va.w += vb.w + vq.w;
      int kq = 4 * k4;
      AsT[(kq+0)*68 + r] = va.x; AsT[(kq+1)*68 + r] = va.y;
      AsT[(kq+2)*68 + r] = va.z; AsT[(kq+3)*68 + r] = va.w;
      int rk = f >> 4, c4 = f & 15;
      float4 vB = B4[(size_t)(h * DD + kk * 32 + rk) * 192 + bcol4 + c4];
      *(float4*)&Bs[rk * 68 + 4 * c4] = vB;
    }
    __syncthreads();
    #pragma unroll
    for (int k = 0; k < 32; k++) {
      float4 a = *(const float4*)&AsT[k * 68 + 4 * ty];
      float4 bb = *(const float4*)&Bs[k * 68 + 4 * tx];
      acc0 = f4fma(a.x, bb, acc0); acc1 = f4fma(a.y, bb, acc1);
      acc2 = f4fma(a.z, bb, acc2); acc3 = f4fma(a.w, bb, acc3);
    }
    __syncthreads();
  }
  int col = nt * 64 + 4 * tx;
  int b0 = arow + 4 * ty;
  *(float4*)&vvout[((size_t)(i * 128 + b0 + 0) * 4 + h) * CC + col] = acc0;
  *(float4*)&vvout[((size_t)(i * 128 + b0 + 1) * 4 + h) * CC + col] = acc1;
  *(float4*)&vvout[((size_t)(i * 128 + b0 + 2) * 4 + h) * CC + col] = acc2;
  *(float4*)&vvout[((size_t)(i * 128 + b0 + 3) * 4 + h) * CC + col] = acc3;
}

// ---------------------------------------------------------------------------
// k_fused: one block per (t, b). Phases:
//   setup: V (12 vv vectors) -> regs; gnorm (3 globals) -> LDS; bias -> LDS
//   A: 196 rows of 16 dots each -> SC tile in LDS (no global sc round-trip)
//   B: softmax over n, minmax, modal mix, rank -> keep flags in LDS
//   C: masked token write (rows re-read from L2/L3-hot lines) + mask write
__global__ __launch_bounds__(256, 2) void k_fused(const float* __restrict__ rgb,
                                                  const float* __restrict__ ni,
                                                  const float* __restrict__ ti,
                                                  const float* __restrict__ vv,
                                                  const float* __restrict__ g0,
                                                  const float* __restrict__ g1,
                                                  const float* __restrict__ g2,
                                                  const float* __restrict__ qpart,
                                                  const float* __restrict__ qb,
                                                  const float* __restrict__ kb,
                                                  const float* __restrict__ modal_w,
                                                  float* __restrict__ out,
                                                  float* __restrict__ outmask) {
  __shared__ float red[4][64 * 17];                 // phase A transpose scratch
  __shared__ __align__(16) float GN[3 * CC];        // normalized globals
  __shared__ float SC[196 * 17];                    // score tile
  __shared__ float BIASs[12];
  __shared__ float CSUM[12];
  __shared__ float SV[3][196];
  __shared__ float MN[3], MX[3];
  __shared__ float sfinal[196];
  __shared__ float keepf[196];

  int bid = blockIdx.x;
  int t = bid >> 7;            // 0..2
  int b = bid & 127;
  int tid = threadIdx.x;
  int w = tid >> 6, lane = tid & 63;
  const float* toks = (t == 0) ? rgb : ((t == 1) ? ni : ti);
  int gi0, gi1, gi2;
  if (t == 0)      { gi0 = 0; gi1 = 1; gi2 = 2; }
  else if (t == 1) { gi0 = 1; gi1 = 0; gi2 = 2; }
  else             { gi0 = 2; gi1 = 0; gi2 = 1; }

  // ---- setup: V vectors into registers (all waves)
  float4 V[36];
  #pragma unroll
  for (int k = 0; k < 3; k++) {
    #pragma unroll
    for (int h = 0; h < 4; h++) {
      const float4* src = (const float4*)(vv + (((size_t)(3*t + k) * 128 + b) * 4 + h) * CC);
      int v = k * 4 + h;
      V[3*v + 0] = src[lane];
      V[3*v + 1] = src[lane + 64];
      V[3*v + 2] = src[lane + 128];
    }
  }

  // ---- setup: gnorm (waves 0..2, one global vector each)
  if (w < 3) {
    int gidx = (w == 0) ? gi0 : ((w == 1) ? gi1 : gi2);
    const float* gsrc = (gidx == 0) ? g0 : ((gidx == 1) ? g1 : g2);
    const float4* s4 = (const float4*)(gsrc + (size_t)b * CC);
    float4 u0 = s4[lane], u1 = s4[lane + 64], u2 = s4[lane + 128];
    float ss = f4dot(u0, u0) + f4dot(u1, u1) + f4dot(u2, u2);
    #pragma unroll
    for (int off = 32; off; off >>= 1) ss += __shfl_xor(ss, off);
    float inv = 1.0f / fmaxf(sqrtf(ss), 1e-12f);
    u0.x *= inv; u0.y *= inv; u0.z *= inv; u0.w *= inv;
    u1.x *= inv; u1.y *= inv; u1.z *= inv; u1.w *= inv;
    u2.x *= inv; u2.y *= inv; u2.z *= inv; u2.w *= inv;
    float4* d4 = (float4*)&GN[w * CC];
    d4[lane] = u0; d4[lane + 64] = u1; d4[lane + 128] = u2;

    // ---- setup: bias for module i = 3t + w (4 heads)
    int i = 3 * t + w;
    const float* qbb = qb + (size_t)i * CC;
    const float* kbb = kb + (size_t)i * CC;
    const float* q0p = qpart + ((size_t)i * 128 + b) * CC;
    const float* q1p = qpart + ((size_t)(9 + i) * 128 + b) * CC;
    #pragma unroll
    for (int h = 0; h < 4; h++) {
      int j0 = h * DD + lane;
      float s = (q0p[j0]       + q1p[j0]       + qbb[j0])       * kbb[j0]
              + (q0p[j0 + 64]  + q1p[j0 + 64]  + qbb[j0 + 64])  * kbb[j0 + 64]
              + (q0p[j0 + 128] + q1p[j0 + 128] + qbb[j0 + 128]) * kbb[j0 + 128];
      #pragma unroll
      for (int off = 32; off; off >>= 1) s += __shfl_xor(s, off);
      if (lane == 0) BIASs[w * 4 + h] = s;
    }
  }
  __syncthreads();   // GN + BIASs visible

  int a_id = lane & 15;
  float bias_r = (a_id < 12) ? BIASs[a_id] : 0.f;

  // ---- phase A: 196 rows, wave w owns rows w, w+4, ...
  float* myred = red[w];
  const float4* G4 = (const float4*)GN;
  int s_grp = lane >> 4;

  const float4* pr0 = (const float4*)(toks + ((size_t)b * NN + w) * CC);
  float4 pc0 = pr0[lane], pc1 = pr0[lane + 64], pc2 = pr0[lane + 128];

  for (int it = 0; it < 49; it++) {
    int row = it * 4 + w;     // < 196 always

    // issue next-row prefetch first (covered by FMA + reduce)
    int rn = row + 4;
    float4 pn0 = pc0, pn1 = pc1, pn2 = pc2;
    if (rn < NN) {
      const float4* pr = (const float4*)(toks + ((size_t)b * NN + rn) * CC);
      pn0 = pr[lane]; pn1 = pr[lane + 64]; pn2 = pr[lane + 128];
    }

    float a[16];
    #pragma unroll
    for (int v = 0; v < 12; v++)
      a[v] = f4dot(pc0, V[3*v]) + f4dot(pc1, V[3*v + 1]) + f4dot(pc2, V[3*v + 2]);
    #pragma unroll
    for (int j = 0; j < 3; j++)
      a[12 + j] = f4dot(pc0, G4[j*192 + lane])
                + f4dot(pc1, G4[j*192 + lane + 64])
                + f4dot(pc2, G4[j*192 + lane + 128]);
    a[15] = f4dot(pc0, pc0) + f4dot(pc1, pc1) + f4dot(pc2, pc2);

    // wave-private LDS transpose reduce (no barrier)
    #pragma unroll
    for (int v = 0; v < 16; v++) myred[lane * 17 + v] = a[v];
    __builtin_amdgcn_s_waitcnt(0xc07f);  // lgkmcnt(0) only; prefetch stays in flight
    __builtin_amdgcn_sched_barrier(0);
    float part = 0.f;
    #pragma unroll
    for (int i2 = 0; i2 < 16; i2++)
      part += myred[(s_grp * 16 + i2) * 17 + a_id];
    part += __shfl_xor(part, 16, 64);
    part += __shfl_xor(part, 32, 64);

    float s15  = __shfl(part, 15, 64);
    float invp = 1.0f / fmaxf(sqrtf(s15), 1e-12f);
    float res;
    if (a_id < 12)      res = (part + bias_r) * SCALE_D;
    else if (a_id < 15) res = part * invp;
    else                res = invp;

    if (lane < 16) SC[row * 17 + lane] = res;
    pc0 = pn0; pc1 = pn1; pc2 = pn2;
  }
  __syncthreads();

  // ---- phase B: softmax over n per (k,h) column, combine, minmax, rank
  bool act = tid < NN;
  for (int c = w; c < 12; c += 4) {
    int n3 = lane + 192;
    float v0 = SC[(lane      ) * 17 + c];
    float v1 = SC[(lane +  64) * 17 + c];
    float v2 = SC[(lane + 128) * 17 + c];
    float v3 = (n3 < NN) ? SC[n3 * 17 + c] : -3.4e38f;
    float mx = fmaxf(fmaxf(v0, v1), fmaxf(v2, v3));
    #pragma unroll
    for (int off = 32; off; off >>= 1) mx = fmaxf(mx, __shfl_xor(mx, off));
    float e0 = expf(v0 - mx), e1 = expf(v1 - mx), e2 = expf(v2 - mx);
    float e3 = (n3 < NN) ? expf(v3 - mx) : 0.f;
    float es = e0 + e1 + e2 + e3;
    #pragma unroll
    for (int off = 32; off; off >>= 1) es += __shfl_xor(es, off);
    SC[(lane      ) * 17 + c] = e0;
    SC[(lane +  64) * 17 + c] = e1;
    SC[(lane + 128) * 17 + c] = e2;
    if (n3 < NN) SC[n3 * 17 + c] = e3;
    if (lane == 0) CSUM[c] = es;
  }
  __syncthreads();

  float scv0 = 0.f, scv1 = 0.f, scv2 = 0.f;
  if (act) {
    const float* r = &SC[tid * 17];
    float as0 = r[0]/CSUM[0] + r[1]/CSUM[1] + r[2]/CSUM[2]  + r[3]/CSUM[3];
    float as1 = r[4]/CSUM[4] + r[5]/CSUM[5] + r[6]/CSUM[6]  + r[7]/CSUM[7];
    float as2 = r[8]/CSUM[8] + r[9]/CSUM[9] + r[10]/CSUM[10] + r[11]/CSUM[11];
    scv0 = r[12] * as0 * 0.25f;
    scv1 = r[13] * as1 * 0.25f;
    scv2 = r[14] * as2 * 0.25f;
    SV[0][tid] = scv0; SV[1][tid] = scv1; SV[2][tid] = scv2;
  }
  __syncthreads();

  if (w < 3) {
    float u0 = SV[w][lane], u1 = SV[w][lane + 64], u2 = SV[w][lane + 128];
    float mn = fminf(fminf(u0, u1), u2);
    float mx = fmaxf(fmaxf(u0, u1), u2);
    if (lane + 192 < NN) {
      float u3 = SV[w][lane + 192];
      mn = fminf(mn, u3); mx = fmaxf(mx, u3);
    }
    #pragma unroll
    for (int off = 32; off; off >>= 1) {
      mn = fminf(mn, __shfl_xor(mn, off));
      mx = fmaxf(mx, __shfl_xor(mx, off));
    }
    if (lane == 0) { MN[w] = mn; MX[w] = mx; }
  }
  __syncthreads();

  float w0 = modal_w[t * 3 + 0], w1 = modal_w[t * 3 + 1], w2 = modal_w[t * 3 + 2];
  float wm = fmaxf(w0, fmaxf(w1, w2));
  float ew0 = expf(w0 - wm), ew1 = expf(w1 - wm), ew2 = expf(w2 - wm);
  float esum = ew0 + ew1 + ew2;
  float fv = 0.f;
  if (act) {
    fv = (ew0 / esum) * (scv0 - MN[0]) / (MX[0] - MN[0] + 1e-8f)
       + (ew1 / esum) * (scv1 - MN[1]) / (MX[1] - MN[1] + 1e-8f)
       + (ew2 / esum) * (scv2 - MN[2]) / (MX[2] - MN[2] + 1e-8f);
    sfinal[tid] = fv;
  }
  __syncthreads();

  if (act) {
    int cnt = 0;
    for (int j = 0; j < NN; j++) {
      float fj = sfinal[j];
      cnt += (fj > fv) || (fj == fv && j < tid);
    }
    float kf = (cnt < NUM_KEEP) ? 1.0f : 0.0f;
    keepf[tid] = kf;
    outmask[((size_t)t * 128 + b) * NN + tid] = kf;
  }
  __syncthreads();

  // ---- phase C: masked token write (token rows L2/L3-hot from phase A)
  float* obase = out + ((size_t)t * 128 + b) * NN * CC;
  for (int r = w; r < NN; r += 4) {
    float4 o0 = {0,0,0,0}, o1 = {0,0,0,0}, o2 = {0,0,0,0};
    if (keepf[r] != 0.0f) {
      const float4* srcr = (const float4*)(toks + ((size_t)b * NN + r) * CC);
      o0 = srcr[lane]; o1 = srcr[lane + 64]; o2 = srcr[lane + 128];
    }
    float4* dstr = (float4*)(obase + (size_t)r * CC);
    dstr[lane] = o0; dstr[lane + 64] = o1; dstr[lane + 128] = o2;
  }
}

// ---------------------------------------------------------------------------
extern "C" void kernel_launch(void* const* d_in, const int* in_sizes, int n_in,
                              void* d_out, int out_size, void* d_ws, size_t ws_size,
                              hipStream_t stream) {
  const float* rgb = (const float*)d_in[0];
  const float* ni  = (const float*)d_in[1];
  const float* ti  = (const float*)d_in[2];
  const float* g0  = (const float*)d_in[3];
  const float* g1  = (const float*)d_in[4];
  const float* g2  = (const float*)d_in[5];
  const float* qw  = (const float*)d_in[6];
  const float* qb  = (const float*)d_in[7];
  const float* kw  = (const float*)d_in[8];
  const float* kb  = (const float*)d_in[9];
  const float* mw  = (const float*)d_in[10];

  float* ws    = (float*)d_ws;
  float* qpart = ws + OFF_QPART;
  float* vv    = ws + OFF_VV;
  float* outf  = (float*)d_out;
  float* maskb = outf + (size_t)3 * TOK_PER;

  k_qproj<<<dim3(24, 9, 2), 256, 0, stream>>>(g0, g1, g2, qw, qpart);
  k_vvproj<<<dim3(24, 36), 256, 0, stream>>>(qpart, qb, kw, vv);
  k_fused<<<384, 256, 0, stream>>>(rgb, ni, ti, vv, g0, g1, g2,
                                   qpart, qb, kb, mw, outf, maskb);
}